// Round 4
// baseline (332.404 us; speedup 1.0000x reference)
//
#include <hip/hip_runtime.h>

#define NSTEP 365
#define NGRID 4000
#define HGRID 2000
#define CAPMIN 0.00125f
#define SMINV 0.0001f
// 365 = 5 * 73, so DEPTH=5 gives a tail-free pipeline
#define DEPTH 5

__device__ __forceinline__ float frcp(float x) { return __builtin_amdgcn_rcpf(x); }
__device__ __forceinline__ float fexp2(float x) { return __builtin_amdgcn_exp2f(x); }
__device__ __forceinline__ float flog2(float x) { return __builtin_amdgcn_logf(x); }

__device__ __forceinline__ void sac_step(
    float c0, float c1, float c2, float c3, float c4,
    float P, float Ep,
    float e1, float f3, float f4, float pfree, float klzp, float klzs,
    float& S1, float& S2, float& S3, float& S4, float& S5,
    float* __restrict__ og, int t, int mu)
{
    // ---- parameter transforms (time-varying 0..4) ----
    const float pctim = c0;                        // lo 0 hi 1
    const float smax  = 1.0f + c1 * 1999.0f;       // lo 1 hi 2000
    const float f1    = 0.005f + c2 * 0.99f;
    const float f2    = 0.005f + c3 * 0.99f;
    const float kuz   = c4;                        // lo 0 hi 1

    const float uztwm = f1 * smax;
    float rem = smax - uztwm;
    const float uzfwm = fmaxf(CAPMIN, f2 * rem);
    rem = rem - uzfwm;
    const float lztwm = fmaxf(CAPMIN, f3 * rem);
    rem = rem - lztwm;
    const float lzfwpm = fmaxf(CAPMIN, f4 * rem);
    const float lzfwsm = fmaxf(CAPMIN, (1.0f - f4) * rem);
    const float pbase  = lzfwpm * klzp + lzfwsm * klzs;
    const float invden = frcp(pbase);
    const float zperc  = fminf(100000.0f,
        (lztwm + lzfwsm * (1.0f - klzs) + lzfwpm * (1.0f - klzp)) * invden);

    const float inv_uztwm = frcp(uztwm);
    const float inv_uzfwm = frcp(uzfwm);
    const float inv_lztwm = frcp(lztwm);

    // ---- fluxes ----
    const float qdir = pctim * P;
    const float peff = (1.0f - pctim) * P;

    const float ru = (S1 * inv_uztwm < S2 * inv_uzfwm)
        ? (S2 * uztwm - S1 * uzfwm) * frcp(uztwm + uzfwm) : 0.0f;

    const float euztw = fminf(S1 * inv_uztwm * Ep, S1);
    const float twexu = (S1 >= uztwm) ? peff : 0.0f;
    const float qsur  = (S2 >= uzfwm) ? twexu : 0.0f;
    const float qint  = kuz * S2;
    const float euzfw = fminf(fmaxf(0.0f, Ep - euztw), S2);

    const float deficit = fmaxf(1e-8f, lztwm - S3)
                        + fmaxf(1e-8f, lzfwpm - S4)
                        + fmaxf(1e-8f, lzfwsm - S5);
    // defmax = max(1e-8, sum) == sum since sum >= 3*CAPMIN; reuse its rcp for
    // both ratio and the soilmoisture_2 denominator (inv3).
    const float defmax     = lztwm + lzfwpm + lzfwsm;
    const float inv_defmax = frcp(defmax);
    const float ratio      = deficit * inv_defmax;
    const float powterm    = fexp2(e1 * flog2(ratio));   // ratio in (0, ~1]
    float pc = pbase * (1.0f + zperc * powterm) * S2 * inv_uzfwm;
    pc = fmaxf(0.0f, fminf(pc, S2));

    const float pctw  = (1.0f - pfree) * pc;
    const float elztw = fminf(S3 * inv_lztwm * fmaxf(0.0f, Ep - euztw - euzfw), S3);
    const float twexl = (S3 >= lztwm) ? pctw : 0.0f;

    // deficit_dist for fp / fs
    const float d1  = fmaxf(0.0f, 1.0f - S4 * frcp(lzfwpm));
    const float d2  = fmaxf(0.0f, 1.0f - S5 * frcp(lzfwsm));
    const float tot = d1 + d2;
    const float invtot = frcp(tot);
    const float invpm  = frcp(lzfwpm + lzfwsm);
    const float fp = (tot > 0.0f) ? d1 * invtot : lzfwpm * invpm;
    const float fs = (tot > 0.0f) ? d2 * invtot : lzfwsm * invpm;

    const float twexlp = fp * twexl;
    const float twexls = fs * twexl;
    const float pcfwp  = pfree * fp * pc;
    const float pcfws  = pfree * fs * pc;

    const float s3r = S3 * inv_lztwm;
    const float rlp = (s3r < (S4 + S5) * invpm) ? (S4 * lztwm - S3 * lzfwpm) * inv_defmax : 0.0f;
    const float rls = (s3r < (S5 + S4) * invpm) ? (S5 * lztwm - S3 * lzfwsm) * inv_defmax : 0.0f;

    const float qbfp = klzp * S4;
    const float qbfs = klzs * S5;

    // ---- state updates ----
    S1 = fmaxf(S1 + peff + ru - euztw - twexu, SMINV);
    S2 = fmaxf(S2 + twexu - euzfw - qsur - qint - ru - pc, SMINV);
    S3 = fmaxf(S3 + pctw + rlp + rls - elztw - twexl, SMINV);
    S4 = fmaxf(S4 + twexlp + pcfwp - rlp - qbfp, SMINV);
    S5 = fmaxf(S5 + twexls + pcfws - rls - qbfs, SMINV);

    float qsim = qdir + qsur + qint + qbfp + qbfs;
    float et   = euztw + euzfw + elztw;

    // ---- mu-mean over the 8-lane group ----
    qsim += __shfl_xor(qsim, 1); qsim += __shfl_xor(qsim, 2); qsim += __shfl_xor(qsim, 4);
    et   += __shfl_xor(et, 1);   et   += __shfl_xor(et, 2);   et   += __shfl_xor(et, 4);

    if (mu == 0) {
        float2 o = make_float2(qsim * 0.125f, et * 0.125f);
        *reinterpret_cast<float2*>(og + (size_t)t * NGRID * 2) = o;
    }
}

// Named-register pipeline slots — NO arrays, NO runtime indexing (avoids scratch).
// Two independent chains (A, B) per thread for ILP-2 latency hiding.
#define DECL_SLOT(c, j) float p0##c##j, p1##c##j, p2##c##j, p3##c##j, p4##c##j, Px##c##j, Ex##c##j;

#define LOAD_SLOT(c, j, pbase, xbase) do {                                \
    const float* pj_ = (pbase) + (size_t)(j) * pstride;                   \
    const float* xj_ = (xbase) + (size_t)(j) * xstride;                   \
    p0##c##j = pj_[0];  p1##c##j = pj_[8];  p2##c##j = pj_[16];           \
    p3##c##j = pj_[24]; p4##c##j = pj_[32];                               \
    Px##c##j = xj_[0];  Ex##c##j = xj_[2];                                \
} while (0)

#define DO_STEP(j) do {                                                          \
    const float a0_=p0A##j, a1_=p1A##j, a2_=p2A##j, a3_=p3A##j, a4_=p4A##j;      \
    const float aP_=PxA##j, aE_=ExA##j;                                          \
    const float b0_=p0B##j, b1_=p1B##j, b2_=p2B##j, b3_=p3B##j, b4_=p4B##j;      \
    const float bP_=PxB##j, bE_=ExB##j;                                          \
    LOAD_SLOT(A, j, pbA, xbA);  /* refill for t+DEPTH */                         \
    LOAD_SLOT(B, j, pbB, xbB);                                                   \
    sac_step(a0_,a1_,a2_,a3_,a4_,aP_,aE_, e1A,f3A,f4A,pfreeA,klzpA,klzsA,        \
             S1A,S2A,S3A,S4A,S5A, ogA, tbase + (j), mu);                         \
    sac_step(b0_,b1_,b2_,b3_,b4_,bP_,bE_, e1B,f3B,f4B,pfreeB,klzpB,klzsB,        \
             S1B,S2B,S3B,S4B,S5B, ogB, tbase + (j), mu);                         \
} while (0)

__global__ __launch_bounds__(64) void sacsma_kernel(
    const float* __restrict__ x,     // [NSTEP][NGRID][3]
    const float* __restrict__ par,   // [NSTEP][NGRID][11][8]
    float* __restrict__ out)         // [NSTEP][NGRID][2]
{
    const int tid = blockIdx.x * 64 + threadIdx.x;   // 16000 threads
    const int gA  = tid >> 3;                        // [0, 2000)
    const int mu  = tid & 7;
    if (gA >= HGRID) return;
    const int gB  = gA + HGRID;                      // [2000, 4000)

    // ---- static params (from t = NSTEP-1), indices 5..10 ----
    const float* psA = par + ((size_t)(NSTEP - 1) * NGRID + gA) * 88 + mu;
    const float* psB = par + ((size_t)(NSTEP - 1) * NGRID + gB) * 88 + mu;
    const float e1A    = 1.0f + psA[5 * 8] * 7.0f;
    const float f3A    = 0.005f + psA[6 * 8] * 0.99f;
    const float f4A    = 0.005f + psA[7 * 8] * 0.99f;
    const float pfreeA = psA[8 * 8];
    const float klzpA  = psA[9 * 8];
    const float klzsA  = psA[10 * 8];
    const float e1B    = 1.0f + psB[5 * 8] * 7.0f;
    const float f3B    = 0.005f + psB[6 * 8] * 0.99f;
    const float f4B    = 0.005f + psB[7 * 8] * 0.99f;
    const float pfreeB = psB[8 * 8];
    const float klzpB  = psB[9 * 8];
    const float klzsB  = psB[10 * 8];

    float S1A = 0.001f, S2A = 0.001f, S3A = 0.001f, S4A = 0.001f, S5A = 0.001f;
    float S1B = 0.001f, S2B = 0.001f, S3B = 0.001f, S4B = 0.001f, S5B = 0.001f;

    const size_t pstride = (size_t)NGRID * 88;   // params per timestep
    const size_t xstride = (size_t)NGRID * 3;
    const float* pgA = par + (size_t)gA * 88 + mu;
    const float* xgA = x + (size_t)gA * 3;
    const float* pgB = par + (size_t)gB * 88 + mu;
    const float* xgB = x + (size_t)gB * 3;
    float* ogA = out + (size_t)gA * 2;
    float* ogB = out + (size_t)gB * 2;

    DECL_SLOT(A,0) DECL_SLOT(A,1) DECL_SLOT(A,2) DECL_SLOT(A,3) DECL_SLOT(A,4)
    DECL_SLOT(B,0) DECL_SLOT(B,1) DECL_SLOT(B,2) DECL_SLOT(B,3) DECL_SLOT(B,4)

    // prime the pipeline: t = 0..4 for both chains
    {
        const float* pbA = pgA; const float* xbA = xgA;
        const float* pbB = pgB; const float* xbB = xgB;
        LOAD_SLOT(A,0,pbA,xbA); LOAD_SLOT(A,1,pbA,xbA); LOAD_SLOT(A,2,pbA,xbA);
        LOAD_SLOT(A,3,pbA,xbA); LOAD_SLOT(A,4,pbA,xbA);
        LOAD_SLOT(B,0,pbB,xbB); LOAD_SLOT(B,1,pbB,xbB); LOAD_SLOT(B,2,pbB,xbB);
        LOAD_SLOT(B,3,pbB,xbB); LOAD_SLOT(B,4,pbB,xbB);
    }

    for (int ob = 0; ob < NSTEP / DEPTH; ++ob) {       // 73 blocks, no tail
        const int tbase = ob * DEPTH;
        // prefetch base for t+DEPTH; last block clamps to t=0 (garbage loads,
        // never consumed — keeps addresses in-bounds with no per-step branch)
        const int pt = (ob < NSTEP / DEPTH - 1) ? (tbase + DEPTH) : 0;
        const float* pbA = pgA + (size_t)pt * pstride;
        const float* xbA = xgA + (size_t)pt * xstride;
        const float* pbB = pgB + (size_t)pt * pstride;
        const float* xbB = xgB + (size_t)pt * xstride;

        DO_STEP(0); DO_STEP(1); DO_STEP(2); DO_STEP(3); DO_STEP(4);
    }
}

extern "C" void kernel_launch(void* const* d_in, const int* in_sizes, int n_in,
                              void* d_out, int out_size, void* d_ws, size_t ws_size,
                              hipStream_t stream) {
    const float* x   = (const float*)d_in[0];   // (365, 4000, 3)
    const float* par = (const float*)d_in[1];   // (365, 4000, 11, 8)
    float* out = (float*)d_out;                 // (365, 4000, 2)

    const int threads = HGRID * 8;              // 16000 threads, 2 chains each
    sacsma_kernel<<<(threads + 63) / 64, 64, 0, stream>>>(x, par, out);
}

// Round 5
// 210.476 us; speedup vs baseline: 1.5793x; 1.5793x over previous
//
#include <hip/hip_runtime.h>
#include <stdint.h>

#define NSTEP 365
#define NGRID 4000
#define CAPMIN 0.00125f
#define SMINV 0.0001f

#define KAHEAD 8               // prefetch depth (steps)
#define NBUF 9                 // KAHEAD+1 so producer never hits consumer slot
#define BUF_DW 384             // 5*64 param dwords + 64 x dwords per slot
#define PSTR_DW (NGRID * 88)   // param dwords per timestep
#define XSTR_DW (NGRID * 3)    // x dwords per timestep

typedef __attribute__((address_space(3))) uint32_t lds_u32_t;
typedef __attribute__((address_space(1))) uint32_t glb_u32_t;

__device__ __forceinline__ void dma4(const float* g, float* l) {
    // global -> LDS direct copy, 4B/lane, LDS dest = base + lane*4
    __builtin_amdgcn_global_load_lds((const glb_u32_t*)(const void*)g,
                                     (lds_u32_t*)(void*)l, 4, 0, 0);
}

__device__ __forceinline__ float frcp(float x) { return __builtin_amdgcn_rcpf(x); }
__device__ __forceinline__ float fexp2(float x) { return __builtin_amdgcn_exp2f(x); }
__device__ __forceinline__ float flog2(float x) { return __builtin_amdgcn_logf(x); }

__device__ __forceinline__ void sac_step(
    float c0, float c1, float c2, float c3, float c4,
    float P, float Ep,
    float e1, float f3, float f4, float pfree, float klzp, float klzs,
    float& S1, float& S2, float& S3, float& S4, float& S5,
    float* __restrict__ og, int t, int mu)
{
    const float pctim = c0;                        // lo 0 hi 1
    const float smax  = 1.0f + c1 * 1999.0f;       // lo 1 hi 2000
    const float f1    = 0.005f + c2 * 0.99f;
    const float f2    = 0.005f + c3 * 0.99f;
    const float kuz   = c4;                        // lo 0 hi 1

    const float uztwm = f1 * smax;
    float rem = smax - uztwm;
    const float uzfwm = fmaxf(CAPMIN, f2 * rem);
    rem = rem - uzfwm;
    const float lztwm = fmaxf(CAPMIN, f3 * rem);
    rem = rem - lztwm;
    const float lzfwpm = fmaxf(CAPMIN, f4 * rem);
    const float lzfwsm = fmaxf(CAPMIN, (1.0f - f4) * rem);
    const float pbase  = lzfwpm * klzp + lzfwsm * klzs;
    const float invden = frcp(pbase);
    const float zperc  = fminf(100000.0f,
        (lztwm + lzfwsm * (1.0f - klzs) + lzfwpm * (1.0f - klzp)) * invden);

    const float inv_uztwm = frcp(uztwm);
    const float inv_uzfwm = frcp(uzfwm);
    const float inv_lztwm = frcp(lztwm);

    const float qdir = pctim * P;
    const float peff = (1.0f - pctim) * P;

    const float ru = (S1 * inv_uztwm < S2 * inv_uzfwm)
        ? (S2 * uztwm - S1 * uzfwm) * frcp(uztwm + uzfwm) : 0.0f;

    const float euztw = fminf(S1 * inv_uztwm * Ep, S1);
    const float twexu = (S1 >= uztwm) ? peff : 0.0f;
    const float qsur  = (S2 >= uzfwm) ? twexu : 0.0f;
    const float qint  = kuz * S2;
    const float euzfw = fminf(fmaxf(0.0f, Ep - euztw), S2);

    const float deficit = fmaxf(1e-8f, lztwm - S3)
                        + fmaxf(1e-8f, lzfwpm - S4)
                        + fmaxf(1e-8f, lzfwsm - S5);
    const float defmax     = lztwm + lzfwpm + lzfwsm;   // >= 3*CAPMIN
    const float inv_defmax = frcp(defmax);
    const float ratio      = deficit * inv_defmax;
    const float powterm    = fexp2(e1 * flog2(ratio));  // ratio in (0, ~1]
    float pc = pbase * (1.0f + zperc * powterm) * S2 * inv_uzfwm;
    pc = fmaxf(0.0f, fminf(pc, S2));

    const float pctw  = (1.0f - pfree) * pc;
    const float elztw = fminf(S3 * inv_lztwm * fmaxf(0.0f, Ep - euztw - euzfw), S3);
    const float twexl = (S3 >= lztwm) ? pctw : 0.0f;

    // deficit_dist: fp, and fs = 1 - fp (exact in both branches)
    const float d1  = fmaxf(0.0f, 1.0f - S4 * frcp(lzfwpm));
    const float d2  = fmaxf(0.0f, 1.0f - S5 * frcp(lzfwsm));
    const float tot = d1 + d2;
    const float pm  = lzfwpm + lzfwsm;
    const float num = (tot > 0.0f) ? d1 : lzfwpm;
    const float den = (tot > 0.0f) ? tot : pm;
    const float fp  = num * frcp(den);
    const float fs  = 1.0f - fp;

    const float twexlp = fp * twexl;
    const float twexls = fs * twexl;
    const float pcfwp  = pfree * fp * pc;
    const float pcfws  = pfree * fs * pc;

    const float invpm = frcp(pm);
    const float s3r   = S3 * inv_lztwm;
    const bool rlmask = s3r < (S4 + S5) * invpm;   // same mask for rlp & rls
    const float rlp = rlmask ? (S4 * lztwm - S3 * lzfwpm) * inv_defmax : 0.0f;
    const float rls = rlmask ? (S5 * lztwm - S3 * lzfwsm) * inv_defmax : 0.0f;

    const float qbfp = klzp * S4;
    const float qbfs = klzs * S5;

    S1 = fmaxf(S1 + peff + ru - euztw - twexu, SMINV);
    S2 = fmaxf(S2 + twexu - euzfw - qsur - qint - ru - pc, SMINV);
    S3 = fmaxf(S3 + pctw + rlp + rls - elztw - twexl, SMINV);
    S4 = fmaxf(S4 + twexlp + pcfwp - rlp - qbfp, SMINV);
    S5 = fmaxf(S5 + twexls + pcfws - rls - qbfs, SMINV);

    float qsim = qdir + qsur + qint + qbfp + qbfs;
    float et   = euztw + euzfw + elztw;

    qsim += __shfl_xor(qsim, 1); qsim += __shfl_xor(qsim, 2); qsim += __shfl_xor(qsim, 4);
    et   += __shfl_xor(et, 1);   et   += __shfl_xor(et, 2);   et   += __shfl_xor(et, 4);

    if (mu == 0) {
        float2 o = make_float2(qsim * 0.125f, et * 0.125f);
        *reinterpret_cast<float2*>(og + (size_t)t * NGRID * 2) = o;
    }
}

__global__ __launch_bounds__(64, 1) void sacsma_kernel(
    const float* __restrict__ x,     // [NSTEP][NGRID][3]
    const float* __restrict__ par,   // [NSTEP][NGRID][11][8]
    float* __restrict__ out)         // [NSTEP][NGRID][2]
{
    __shared__ float lds[NBUF * BUF_DW];   // 13824 B

    const int lane = threadIdx.x;          // 0..63
    const int g0   = blockIdx.x * 8;       // 8 grids per workgroup
    const int gl   = lane >> 3;
    const int mu   = lane & 7;
    const int g    = g0 + gl;

    // ---- static params (t = NSTEP-1, indices 5..10); consumed BEFORE the
    // DMA pipeline starts so no compiler vmcnt waits land inside the loop ----
    const float* ps = par + ((size_t)(NSTEP - 1) * NGRID + g) * 88 + mu;
    const float e1    = 1.0f + ps[5 * 8] * 7.0f;
    const float f3    = 0.005f + ps[6 * 8] * 0.99f;
    const float f4    = 0.005f + ps[7 * 8] * 0.99f;
    const float pfree = ps[8 * 8];
    const float klzp  = ps[9 * 8];
    const float klzs  = ps[10 * 8];

    // ---- per-lane DMA source offsets ----
    // params: instr i, lane l -> par[t][g0 + (l>>3)][i][l&7]
    const int poff = (g0 + gl) * 88 + mu;          // dwords; +i*8 per plane
    // x: lanes 0..23 -> x[t][g0 + xl/3][xl%3]; lanes >=24 duplicate (harmless)
    int xl = lane; if (xl >= 24) xl -= 24; if (xl >= 24) xl -= 24;
    const int xq = xl / 3;
    const int xoff = (g0 + xq) * 3 + (xl - xq * 3);

    const float* pp = par + poff;
    const float* px = x + xoff;

    // ---- prologue: fill slots 0..KAHEAD-1 with t=0..KAHEAD-1 ----
    #pragma unroll
    for (int j = 0; j < KAHEAD; ++j) {
        float* lb = lds + j * BUF_DW;
        const float* pj = pp + (size_t)j * PSTR_DW;
        dma4(pj + 0,  lb + 0);
        dma4(pj + 8,  lb + 64);
        dma4(pj + 16, lb + 128);
        dma4(pj + 24, lb + 192);
        dma4(pj + 32, lb + 256);
        dma4(px + (size_t)j * XSTR_DW, lb + 320);
    }

    float S1 = 0.001f, S2 = 0.001f, S3 = 0.001f, S4 = 0.001f, S5 = 0.001f;
    float* og = out + (size_t)g * 2;

    const float* ppn = pp + (size_t)KAHEAD * PSTR_DW;   // producer: t+KAHEAD
    const float* pxn = px + (size_t)KAHEAD * XSTR_DW;
    int coff = 0;                    // consumer slot offset (dwords)
    int woff = KAHEAD * BUF_DW;      // producer slot offset (dwords)

    for (int t = 0; t < NSTEP; ++t) {
        // ---- produce slot for t+KAHEAD (6 DMAs; never drained) ----
        float* lb = lds + woff;
        dma4(ppn + 0,  lb + 0);
        dma4(ppn + 8,  lb + 64);
        dma4(ppn + 16, lb + 128);
        dma4(ppn + 24, lb + 192);
        dma4(ppn + 32, lb + 256);
        dma4(pxn,      lb + 320);
        ppn += PSTR_DW; pxn += XSTR_DW;
        if (t + KAHEAD + 1 >= NSTEP) { ppn = pp; pxn = px; }  // clamp (garbage, unread)
        woff += BUF_DW; if (woff == NBUF * BUF_DW) woff = 0;

        // ---- counted wait: 8 steps x 6 loads in flight after slot-t's own ----
        asm volatile("s_waitcnt vmcnt(48)" ::: "memory");

        // ---- consume slot t (conflict-free lane-linear reads) ----
        const float c0 = lds[coff + lane];
        const float c1 = lds[coff + 64 + lane];
        const float c2 = lds[coff + 128 + lane];
        const float c3 = lds[coff + 192 + lane];
        const float c4 = lds[coff + 256 + lane];
        const float P  = lds[coff + 320 + gl * 3];
        const float Ep = lds[coff + 322 + gl * 3];
        coff += BUF_DW; if (coff == NBUF * BUF_DW) coff = 0;

        sac_step(c0, c1, c2, c3, c4, P, Ep,
                 e1, f3, f4, pfree, klzp, klzs,
                 S1, S2, S3, S4, S5, og, t, mu);
    }
}

extern "C" void kernel_launch(void* const* d_in, const int* in_sizes, int n_in,
                              void* d_out, int out_size, void* d_ws, size_t ws_size,
                              hipStream_t stream) {
    const float* x   = (const float*)d_in[0];   // (365, 4000, 3)
    const float* par = (const float*)d_in[1];   // (365, 4000, 11, 8)
    float* out = (float*)d_out;                 // (365, 4000, 2)

    sacsma_kernel<<<NGRID / 8, 64, 0, stream>>>(x, par, out);  // 500 WGs x 64
}

// Round 7
// 129.612 us; speedup vs baseline: 2.5646x; 1.6239x over previous
//
#include <hip/hip_runtime.h>
#include <stdint.h>

#define NSTEP 365
#define NGRID 4000
#define CAPMIN 0.00125f
#define SMINV 0.0001f

#define BUF_DW 384            // 5*64 param dwords + 64 x dwords per slot
#define NSLOT 20              // 4 regions x 5 slots
#define PSTR_DW (NGRID * 88)
#define XSTR_DW (NGRID * 3)

typedef __attribute__((address_space(3))) uint32_t lds_u32_t;
typedef __attribute__((address_space(1))) uint32_t glb_u32_t;

__device__ __forceinline__ void dma4(const float* g, float* l) {
    // global -> LDS direct, 4B/lane, LDS dest = uniform base + lane*4
    __builtin_amdgcn_global_load_lds((const glb_u32_t*)(const void*)g,
                                     (lds_u32_t*)(void*)l, 4, 0, 0);
}

__device__ __forceinline__ float frcp(float x) { return __builtin_amdgcn_rcpf(x); }
__device__ __forceinline__ float fexp2(float x) { return __builtin_amdgcn_exp2f(x); }
__device__ __forceinline__ float flog2(float x) { return __builtin_amdgcn_logf(x); }

// One step of SAC-SMA. No cross-lane ops, no stores.
__device__ __forceinline__ void sac_step(
    float c0, float c1, float c2, float c3, float c4,
    float P, float Ep,
    float e1, float f3, float f4, float pfree, float klzp, float klzs,
    float& S1, float& S2, float& S3, float& S4, float& S5,
    float& qsim, float& et)
{
    const float pctim = c0;                        // lo 0 hi 1
    const float smax  = 1.0f + c1 * 1999.0f;       // lo 1 hi 2000
    const float f1    = 0.005f + c2 * 0.99f;
    const float f2    = 0.005f + c3 * 0.99f;
    const float kuz   = c4;                        // lo 0 hi 1

    const float uztwm = f1 * smax;
    float rem = smax - uztwm;
    const float uzfwm = fmaxf(CAPMIN, f2 * rem);
    rem = rem - uzfwm;
    const float lztwm = fmaxf(CAPMIN, f3 * rem);
    rem = rem - lztwm;
    const float lzfwpm = fmaxf(CAPMIN, f4 * rem);
    const float lzfwsm = fmaxf(CAPMIN, (1.0f - f4) * rem);
    const float pbase  = lzfwpm * klzp + lzfwsm * klzs;
    const float invden = frcp(pbase);
    const float zperc  = fminf(100000.0f,
        (lztwm + lzfwsm * (1.0f - klzs) + lzfwpm * (1.0f - klzp)) * invden);

    const float inv_uztwm = frcp(uztwm);
    const float inv_uzfwm = frcp(uzfwm);
    const float inv_lztwm = frcp(lztwm);

    const float qdir = pctim * P;
    const float peff = (1.0f - pctim) * P;

    const float ru = (S1 * inv_uztwm < S2 * inv_uzfwm)
        ? (S2 * uztwm - S1 * uzfwm) * frcp(uztwm + uzfwm) : 0.0f;

    const float euztw = fminf(S1 * inv_uztwm * Ep, S1);
    const float twexu = (S1 >= uztwm) ? peff : 0.0f;
    const float qsur  = (S2 >= uzfwm) ? twexu : 0.0f;
    const float qint  = kuz * S2;
    const float euzfw = fminf(fmaxf(0.0f, Ep - euztw), S2);

    const float deficit = fmaxf(1e-8f, lztwm - S3)
                        + fmaxf(1e-8f, lzfwpm - S4)
                        + fmaxf(1e-8f, lzfwsm - S5);
    const float defmax     = lztwm + lzfwpm + lzfwsm;   // >= 3*CAPMIN
    const float inv_defmax = frcp(defmax);
    const float ratio      = deficit * inv_defmax;
    const float powterm    = fexp2(e1 * flog2(ratio));  // ratio in (0, ~1]
    float pc = pbase * (1.0f + zperc * powterm) * S2 * inv_uzfwm;
    pc = fmaxf(0.0f, fminf(pc, S2));

    const float pctw  = (1.0f - pfree) * pc;
    const float elztw = fminf(S3 * inv_lztwm * fmaxf(0.0f, Ep - euztw - euzfw), S3);
    const float twexl = (S3 >= lztwm) ? pctw : 0.0f;

    // deficit_dist: fp, and fs = 1 - fp (exact in both branches)
    const float d1  = fmaxf(0.0f, 1.0f - S4 * frcp(lzfwpm));
    const float d2  = fmaxf(0.0f, 1.0f - S5 * frcp(lzfwsm));
    const float tot = d1 + d2;
    const float pm  = lzfwpm + lzfwsm;
    const float num = (tot > 0.0f) ? d1 : lzfwpm;
    const float den = (tot > 0.0f) ? tot : pm;
    const float fp  = num * frcp(den);
    const float fs  = 1.0f - fp;

    const float twexlp = fp * twexl;
    const float twexls = fs * twexl;
    const float pcfwp  = pfree * fp * pc;
    const float pcfws  = pfree * fs * pc;

    const float invpm = frcp(pm);
    const float s3r   = S3 * inv_lztwm;
    const bool rlmask = s3r < (S4 + S5) * invpm;   // same mask for rlp & rls
    const float rlp = rlmask ? (S4 * lztwm - S3 * lzfwpm) * inv_defmax : 0.0f;
    const float rls = rlmask ? (S5 * lztwm - S3 * lzfwsm) * inv_defmax : 0.0f;

    const float qbfp = klzp * S4;
    const float qbfs = klzs * S5;

    S1 = fmaxf(S1 + peff + ru - euztw - twexu, SMINV);
    S2 = fmaxf(S2 + twexu - euzfw - qsur - qint - ru - pc, SMINV);
    S3 = fmaxf(S3 + pctw + rlp + rls - elztw - twexl, SMINV);
    S4 = fmaxf(S4 + twexlp + pcfwp - rlp - qbfp, SMINV);
    S5 = fmaxf(S5 + twexls + pcfws - rls - qbfs, SMINV);

    qsim = qdir + qsur + qint + qbfp + qbfs;
    et   = euztw + euzfw + elztw;
}

__device__ __forceinline__ void issue_slot(const float* pp, const float* px,
                                           int t, float* dst) {
    const float* pj = pp + (size_t)t * PSTR_DW;
    dma4(pj,      dst);          // param plane 0
    dma4(pj + 8,  dst + 64);     // plane 1
    dma4(pj + 16, dst + 128);    // plane 2
    dma4(pj + 24, dst + 192);    // plane 3
    dma4(pj + 32, dst + 256);    // plane 4
    dma4(px + (size_t)t * XSTR_DW, dst + 320);   // x plane (P, Ep)
}

__global__ __launch_bounds__(128, 1) void sacsma_kernel(
    const float* __restrict__ x,     // [NSTEP][NGRID][3]
    const float* __restrict__ par,   // [NSTEP][NGRID][11][8]
    float* __restrict__ out)         // [NSTEP][NGRID][2]
{
    __shared__ __align__(16) float lds[NSLOT * BUF_DW];   // 30720 B ring
    __shared__ __align__(16) float smq[5 * 64];           // reduction staging
    __shared__ __align__(16) float sme[5 * 64];

    const int wave = threadIdx.x >> 6;
    const int lane = threadIdx.x & 63;
    const int g0   = blockIdx.x * 8;       // 8 grids per workgroup

    if (wave == 0) {
        // ================= PRODUCER WAVE =================
        const int gl = lane >> 3;
        const int mu = lane & 7;
        const float* pp = par + (size_t)(g0 + gl) * 88 + mu;
        int xl = lane; if (xl >= 24) xl -= 24; if (xl >= 24) xl -= 24;
        const int xq = xl / 3;
        const float* px = x + (g0 + xq) * 3 + (xl - xq * 3);

        // prologue: batches 0,1 (t = 0..9 -> slots 0..9, regions 0,1)
        #pragma unroll
        for (int j = 0; j < 10; ++j)
            issue_slot(pp, px, j, lds + j * BUF_DW);

        for (int i = 0; i < NSTEP / 5; ++i) {          // 73 iterations
            // batch i fully retired (only batch i+1's 30 DMAs may remain)
            asm volatile("s_waitcnt vmcnt(30)" ::: "memory");
            // issue batch i+2 into region (i+2)&3 (writer region never equals
            // any region the consumer reads concurrently: distance 3 mod 4)
            float* dst = lds + (((i + 2) & 3) * 5) * BUF_DW;
            int tb = 5 * (i + 2);
            if (tb >= NSTEP) tb -= NSTEP;              // garbage src, valid addr
            #pragma unroll
            for (int j = 0; j < 5; ++j)
                issue_slot(pp, px, tb + j, dst + j * BUF_DW);
            __builtin_amdgcn_s_barrier();              // raw: no vmcnt(0) drain
        }
    } else {
        // ================= CONSUMER WAVE =================
        const int gl = lane >> 3;
        const int mu = lane & 7;
        const int g  = g0 + gl;

        // static params (t = NSTEP-1, indices 5..10) — plain loads, pre-loop
        const float* ps = par + ((size_t)(NSTEP - 1) * NGRID + g) * 88 + mu;
        const float e1    = 1.0f + ps[5 * 8] * 7.0f;
        const float f3    = 0.005f + ps[6 * 8] * 0.99f;
        const float f4    = 0.005f + ps[7 * 8] * 0.99f;
        const float pfree = ps[8 * 8];
        const float klzp  = ps[9 * 8];
        const float klzs  = ps[10 * 8];

        float S1 = 0.001f, S2 = 0.001f, S3 = 0.001f, S4 = 0.001f, S5 = 0.001f;

        for (int i = 0; i < NSTEP / 5; ++i) {          // 73 iterations
            __builtin_amdgcn_s_barrier();              // batch i ready
            const int rbase = (i & 3) * (5 * BUF_DW);
            const int tbase = i * 5;

            #pragma unroll
            for (int j = 0; j < 5; ++j) {
                const float* sb = lds + rbase + j * BUF_DW;
                const float c0 = sb[lane];
                const float c1 = sb[64 + lane];
                const float c2 = sb[128 + lane];
                const float c3 = sb[192 + lane];
                const float c4 = sb[256 + lane];
                const float P  = sb[320 + gl * 3];
                const float Ep = sb[322 + gl * 3];
                float qs, ev;
                sac_step(c0, c1, c2, c3, c4, P, Ep,
                         e1, f3, f4, pfree, klzp, klzs,
                         S1, S2, S3, S4, S5, qs, ev);
                smq[j * 64 + lane] = qs;
                sme[j * 64 + lane] = ev;
            }

            // batched mu-reduction + coalesced store for the 5-step block
            if (lane < 40) {
                const int s  = lane >> 3;
                const int gg = lane & 7;
                const float4* q4 = reinterpret_cast<const float4*>(&smq[s * 64 + gg * 8]);
                const float4* e4 = reinterpret_cast<const float4*>(&sme[s * 64 + gg * 8]);
                const float4 qa = q4[0], qb = q4[1];
                const float4 ea = e4[0], eb = e4[1];
                const float qsum = ((qa.x + qa.y) + (qa.z + qa.w))
                                 + ((qb.x + qb.y) + (qb.z + qb.w));
                const float esum = ((ea.x + ea.y) + (ea.z + ea.w))
                                 + ((eb.x + eb.y) + (eb.z + eb.w));
                float2 o = make_float2(qsum * 0.125f, esum * 0.125f);
                *reinterpret_cast<float2*>(
                    out + ((size_t)(tbase + s) * NGRID + g0 + gg) * 2) = o;
            }
        }
    }
}

extern "C" void kernel_launch(void* const* d_in, const int* in_sizes, int n_in,
                              void* d_out, int out_size, void* d_ws, size_t ws_size,
                              hipStream_t stream) {
    const float* x   = (const float*)d_in[0];   // (365, 4000, 3)
    const float* par = (const float*)d_in[1];   // (365, 4000, 11, 8)
    float* out = (float*)d_out;                 // (365, 4000, 2)

    sacsma_kernel<<<NGRID / 8, 128, 0, stream>>>(x, par, out);  // 500 WGs x 2 waves
}

// Round 8
// 121.648 us; speedup vs baseline: 2.7325x; 1.0655x over previous
//
#include <hip/hip_runtime.h>
#include <stdint.h>

#define NSTEP 365
#define NGRID 4000
#define CAPMIN 0.00125f
#define SMINV 0.0001f
#define PSTR_DW (NGRID * 88)
#define XSTR_DW (NGRID * 3)

// LDS layout (dwords):
//   raw ring:     3 regions x 5 slots x 384  = 5760   [0, 5760)
//   derived ring: 2 regions x 5 slots x 960  = 9600   [5760, 15360)
//   smq staging:  5 x 64                     = 320    [15360, 15680)
//   sme staging:  5 x 64                     = 320    [15680, 16000)
#define RAW_SLOT 384
#define RAW_REG  (5 * RAW_SLOT)
#define DER_SLOT 960
#define DER_REG  (5 * DER_SLOT)
#define DER_BASE 5760
#define SMQ_BASE 15360
#define SME_BASE 15680

typedef __attribute__((address_space(3))) uint32_t lds_u32_t;
typedef __attribute__((address_space(1))) uint32_t glb_u32_t;

__device__ __forceinline__ void dma4(const float* g, float* l) {
    __builtin_amdgcn_global_load_lds((const glb_u32_t*)(const void*)g,
                                     (lds_u32_t*)(void*)l, 4, 0, 0);
}

__device__ __forceinline__ float frcp(float x) { return __builtin_amdgcn_rcpf(x); }
__device__ __forceinline__ float fexp2(float x) { return __builtin_amdgcn_exp2f(x); }
__device__ __forceinline__ float flog2(float x) { return __builtin_amdgcn_logf(x); }

__device__ __forceinline__ void issue_slot(const float* pp, const float* px,
                                           int t, float* dst) {
    const float* pj = pp + (size_t)t * PSTR_DW;
    dma4(pj,      dst);
    dma4(pj + 8,  dst + 64);
    dma4(pj + 16, dst + 128);
    dma4(pj + 24, dst + 192);
    dma4(pj + 32, dst + 256);
    dma4(px + (size_t)t * XSTR_DW, dst + 320);
}

__global__ __launch_bounds__(192, 1) void sacsma_kernel(
    const float* __restrict__ x,     // [NSTEP][NGRID][3]
    const float* __restrict__ par,   // [NSTEP][NGRID][11][8]
    float* __restrict__ out)         // [NSTEP][NGRID][2]
{
    __shared__ __align__(16) float lds[16000];   // 64000 B

    const int wave = threadIdx.x >> 6;
    const int lane = threadIdx.x & 63;
    const int g0   = blockIdx.x * 8;
    const int gl   = lane >> 3;
    const int mu   = lane & 7;
    const int g    = g0 + gl;

    if (wave == 0) {
        // ===== DMA producer: lead-1 batch, counted wait, never drains consumer =====
        const float* pp = par + (size_t)g * 88 + mu;
        int xl = lane; if (xl >= 24) xl -= 24; if (xl >= 24) xl -= 24;
        const int xq = xl / 3;
        const float* px = x + (g0 + xq) * 3 + (xl - xq * 3);

        // prologue: batch 0 -> raw region 0
        #pragma unroll
        for (int j = 0; j < 5; ++j)
            issue_slot(pp, px, j, lds + j * RAW_SLOT);

        for (int i = 0; i < 75; ++i) {
            // batch i (issued last iter, ~1 full iter ago) must be retired
            asm volatile("s_waitcnt vmcnt(0)" ::: "memory");
            if (i <= 71) {
                const int b = i + 1;                       // batches 1..72
                float* dst = lds + (b % 3) * RAW_REG;
                const int tb = 5 * b;
                #pragma unroll
                for (int j = 0; j < 5; ++j)
                    issue_slot(pp, px, tb + j, dst + j * RAW_SLOT);
            }
            asm volatile("s_barrier" ::: "memory");
        }
    } else if (wave == 1) {
        // ===== transform wave: raw -> derived (param-only math, no VMEM in loop) =====
        const float* ps = par + ((size_t)(NSTEP - 1) * NGRID + g) * 88 + mu;
        const float f3   = 0.005f + ps[6 * 8] * 0.99f;
        const float f4   = 0.005f + ps[7 * 8] * 0.99f;
        const float klzp = ps[9 * 8];
        const float klzs = ps[10 * 8];

        for (int i = 0; i < 75; ++i) {
            if (i >= 1 && i <= 73) {
                const int b = i - 1;                       // batches 0..72
                const float* rreg = lds + (b % 3) * RAW_REG;
                float* dreg = lds + DER_BASE + (b & 1) * DER_REG;
                #pragma unroll
                for (int j = 0; j < 5; ++j) {
                    const float* rb = rreg + j * RAW_SLOT;
                    float* db = dreg + j * DER_SLOT;

                    const float c0 = rb[lane];
                    const float c1 = rb[64 + lane];
                    const float c2 = rb[128 + lane];
                    const float c3 = rb[192 + lane];
                    const float c4 = rb[256 + lane];
                    const float P  = rb[320 + gl * 3];
                    const float Ep = rb[322 + gl * 3];

                    const float smaxv = 1.0f + c1 * 1999.0f;
                    const float f1 = 0.005f + c2 * 0.99f;
                    const float f2 = 0.005f + c3 * 0.99f;
                    const float uztwm = f1 * smaxv;
                    float rem = smaxv - uztwm;
                    const float uzfwm = fmaxf(CAPMIN, f2 * rem);
                    rem -= uzfwm;
                    const float lztwm = fmaxf(CAPMIN, f3 * rem);
                    rem -= lztwm;
                    const float lzfwpm = fmaxf(CAPMIN, f4 * rem);
                    const float lzfwsm = fmaxf(CAPMIN, (1.0f - f4) * rem);
                    const float pbase = lzfwpm * klzp + lzfwsm * klzs;
                    // pbase*zperc without divide: min(raw_num, 1e5*pbase)
                    const float pz = fminf(lztwm + lzfwsm * (1.0f - klzs)
                                           + lzfwpm * (1.0f - klzp),
                                           100000.0f * pbase);
                    const float inv_uztwm = frcp(uztwm);
                    const float inv_uzfwm = frcp(uzfwm);
                    const float inv_lztwm = frcp(lztwm);
                    const float inv_uzsum = frcp(uztwm + uzfwm);
                    const float qdir = c0 * P;
                    const float peff = (1.0f - c0) * P;

                    float2* d2 = reinterpret_cast<float2*>(db);
                    d2[0 * 64 + lane] = make_float2(qdir, peff);
                    d2[1 * 64 + lane] = make_float2(Ep, c4);            // Ep, kuz
                    d2[2 * 64 + lane] = make_float2(uztwm, uzfwm);
                    d2[3 * 64 + lane] = make_float2(inv_uztwm, inv_uzfwm);
                    d2[4 * 64 + lane] = make_float2(inv_uzsum, lztwm);
                    d2[5 * 64 + lane] = make_float2(inv_lztwm, pbase);
                    d2[6 * 64 + lane] = make_float2(lzfwpm, lzfwsm);
                    db[896 + lane] = pz;
                }
                asm volatile("s_waitcnt lgkmcnt(0)" ::: "memory");
            }
            asm volatile("s_barrier" ::: "memory");
        }
    } else {
        // ===== state wave: pure recurrence, minimal instruction count =====
        const float* ps = par + ((size_t)(NSTEP - 1) * NGRID + g) * 88 + mu;
        const float e1    = 1.0f + ps[5 * 8] * 7.0f;
        const float pfree = ps[8 * 8];
        const float klzp  = ps[9 * 8];
        const float klzs  = ps[10 * 8];

        float S1 = 0.001f, S2 = 0.001f, S3 = 0.001f, S4 = 0.001f, S5 = 0.001f;
        float* smq = lds + SMQ_BASE;
        float* sme = lds + SME_BASE;

        for (int i = 0; i < 75; ++i) {
            if (i >= 2) {
                const int b = i - 2;                       // batches 0..72
                const float* dreg = lds + DER_BASE + (b & 1) * DER_REG;
                #pragma unroll
                for (int j = 0; j < 5; ++j) {
                    const float* db = dreg + j * DER_SLOT;
                    const float2* d2 = reinterpret_cast<const float2*>(db);
                    const float2 v0 = d2[0 * 64 + lane];   // qdir, peff
                    const float2 v1 = d2[1 * 64 + lane];   // Ep, kuz
                    const float2 v2 = d2[2 * 64 + lane];   // uztwm, uzfwm
                    const float2 v3 = d2[3 * 64 + lane];   // inv_uztwm, inv_uzfwm
                    const float2 v4 = d2[4 * 64 + lane];   // inv_uzsum, lztwm
                    const float2 v5 = d2[5 * 64 + lane];   // inv_lztwm, pbase
                    const float2 v6 = d2[6 * 64 + lane];   // lzfwpm, lzfwsm
                    const float pz = db[896 + lane];
                    const float qdir = v0.x, peff = v0.y;
                    const float Ep = v1.x, kuz = v1.y;
                    const float uztwm = v2.x, uzfwm = v2.y;
                    const float inv_uztwm = v3.x, inv_uzfwm = v3.y;
                    const float inv_uzsum = v4.x, lztwm = v4.y;
                    const float inv_lztwm = v5.x, pbase = v5.y;
                    const float lzfwpm = v6.x, lzfwsm = v6.y;

                    const float rud = S2 * uztwm - S1 * uzfwm;
                    const float ru  = (rud > 0.0f) ? rud * inv_uzsum : 0.0f;
                    const float euztw = fminf(S1 * inv_uztwm * Ep, S1);
                    const float twexu = (S1 >= uztwm) ? peff : 0.0f;
                    const float qsur  = (S2 >= uzfwm) ? twexu : 0.0f;
                    const float qint  = kuz * S2;
                    const float euzfw = fminf(fmaxf(0.0f, Ep - euztw), S2);

                    const float deficit = fmaxf(1e-8f, lztwm - S3)
                                        + fmaxf(1e-8f, lzfwpm - S4)
                                        + fmaxf(1e-8f, lzfwsm - S5);
                    const float defmax = lztwm + lzfwpm + lzfwsm;
                    const float inv_defmax = frcp(defmax);
                    const float powterm = fexp2(e1 * flog2(deficit * inv_defmax));
                    float pc = (pbase + pz * powterm) * S2 * inv_uzfwm;
                    pc = fmaxf(0.0f, fminf(pc, S2));

                    const float pctw  = (1.0f - pfree) * pc;
                    const float elztw = fminf(S3 * inv_lztwm
                                              * fmaxf(0.0f, Ep - euztw - euzfw), S3);
                    const float twexl = (S3 >= lztwm) ? pctw : 0.0f;

                    const float aa  = fmaxf(0.0f, lzfwpm - S4) * lzfwsm;
                    const float bb  = fmaxf(0.0f, lzfwsm - S5) * lzfwpm;
                    const float den = aa + bb;
                    const float pm  = lzfwpm + lzfwsm;
                    const float fp  = ((den > 0.0f) ? aa : lzfwpm)
                                    * frcp((den > 0.0f) ? den : pm);
                    const float fs  = 1.0f - fp;

                    const float twexlp = fp * twexl;
                    const float twexls = fs * twexl;
                    const float pcfwp  = pfree * fp * pc;
                    const float pcfws  = pfree * fs * pc;

                    const bool rlm = S3 * pm < (S4 + S5) * lztwm;
                    const float rlp = rlm ? (S4 * lztwm - S3 * lzfwpm) * inv_defmax : 0.0f;
                    const float rls = rlm ? (S5 * lztwm - S3 * lzfwsm) * inv_defmax : 0.0f;

                    const float qbfp = klzp * S4;
                    const float qbfs = klzs * S5;

                    S1 = fmaxf(S1 + peff + ru - euztw - twexu, SMINV);
                    S2 = fmaxf(S2 + twexu - euzfw - qsur - qint - ru - pc, SMINV);
                    S3 = fmaxf(S3 + pctw + rlp + rls - elztw - twexl, SMINV);
                    S4 = fmaxf(S4 + twexlp + pcfwp - rlp - qbfp, SMINV);
                    S5 = fmaxf(S5 + twexls + pcfws - rls - qbfs, SMINV);

                    smq[j * 64 + lane] = qdir + qsur + qint + qbfp + qbfs;
                    sme[j * 64 + lane] = euztw + euzfw + elztw;
                }

                // batched mu-reduction + coalesced store for this 5-step block
                if (lane < 40) {
                    const int s  = lane >> 3;
                    const int gg = lane & 7;
                    const float4* q4 = reinterpret_cast<const float4*>(&smq[s * 64 + gg * 8]);
                    const float4* e4 = reinterpret_cast<const float4*>(&sme[s * 64 + gg * 8]);
                    const float4 qa = q4[0], qb = q4[1];
                    const float4 ea = e4[0], eb = e4[1];
                    const float qsum = ((qa.x + qa.y) + (qa.z + qa.w))
                                     + ((qb.x + qb.y) + (qb.z + qb.w));
                    const float esum = ((ea.x + ea.y) + (ea.z + ea.w))
                                     + ((eb.x + eb.y) + (eb.z + eb.w));
                    float2 o = make_float2(qsum * 0.125f, esum * 0.125f);
                    *reinterpret_cast<float2*>(
                        out + ((size_t)(5 * b + s) * NGRID + g0 + gg) * 2) = o;
                }
            }
            asm volatile("s_barrier" ::: "memory");
        }
    }
}

extern "C" void kernel_launch(void* const* d_in, const int* in_sizes, int n_in,
                              void* d_out, int out_size, void* d_ws, size_t ws_size,
                              hipStream_t stream) {
    const float* x   = (const float*)d_in[0];   // (365, 4000, 3)
    const float* par = (const float*)d_in[1];   // (365, 4000, 11, 8)
    float* out = (float*)d_out;                 // (365, 4000, 2)

    sacsma_kernel<<<NGRID / 8, 192, 0, stream>>>(x, par, out);  // 500 WGs x 3 waves
}

// Round 9
// 106.479 us; speedup vs baseline: 3.1218x; 1.1425x over previous
//
#include <hip/hip_runtime.h>
#include <stdint.h>

#define NSTEP 365
#define NGRID 4000
#define CAPMIN 0.00125f
#define SMINV 0.0001f
#define PSTR_DW (NGRID * 88)
#define XSTR_DW (NGRID * 3)

// LDS layout (dwords), total 16000 dw = 64000 B:
//   raw ring:     4 regions x 5 slots x 384 = 7680   [0, 7680)
//   derived ring: 2 regions x 5 slots x 768 = 7680   [7680, 15360)
//   smq staging:  5 x 64 = 320                       [15360, 15680)
//   sme staging:  5 x 64 = 320                       [15680, 16000)
#define RAW_SLOT 384
#define RAW_REG  (5 * RAW_SLOT)
#define DER_BASE 7680
#define DER_SLOT 768            // 6 float2 rows x 64 lanes
#define DER_REG  (5 * DER_SLOT)
#define SMQ_BASE 15360
#define SME_BASE 15680

typedef __attribute__((address_space(3))) uint32_t lds_u32_t;
typedef __attribute__((address_space(1))) uint32_t glb_u32_t;

__device__ __forceinline__ void dma4(const float* g, float* l) {
    __builtin_amdgcn_global_load_lds((const glb_u32_t*)(const void*)g,
                                     (lds_u32_t*)(void*)l, 4, 0, 0);
}

__device__ __forceinline__ float frcp(float x) { return __builtin_amdgcn_rcpf(x); }
__device__ __forceinline__ float fexp2(float x) { return __builtin_amdgcn_exp2f(x); }
__device__ __forceinline__ float flog2(float x) { return __builtin_amdgcn_logf(x); }

__device__ __forceinline__ void issue_slot(const float* pp, const float* px,
                                           int t, float* dst) {
    const float* pj = pp + (size_t)t * PSTR_DW;
    dma4(pj,      dst);
    dma4(pj + 8,  dst + 64);
    dma4(pj + 16, dst + 128);
    dma4(pj + 24, dst + 192);
    dma4(pj + 32, dst + 256);
    dma4(px + (size_t)t * XSTR_DW, dst + 320);
}

// ---- state wave: hoisted reads (named registers, static addresses) ----
#define RDS(j)                                                               \
    const float  c0_##j = rreg[(j) * RAW_SLOT + lane];                       \
    const float  kz_##j = rreg[(j) * RAW_SLOT + 256 + lane];                 \
    const float  Pp_##j = rreg[(j) * RAW_SLOT + 320 + gl3];                  \
    const float  Ee_##j = rreg[(j) * RAW_SLOT + 322 + gl3];                  \
    const float2 dA_##j = dreg[(j) * 384 + lane];                            \
    const float2 dB_##j = dreg[(j) * 384 + 64 + lane];                       \
    const float2 dC_##j = dreg[(j) * 384 + 128 + lane];                      \
    const float2 dD_##j = dreg[(j) * 384 + 192 + lane];                      \
    const float2 dE_##j = dreg[(j) * 384 + 256 + lane];                      \
    const float2 dF_##j = dreg[(j) * 384 + 320 + lane];

#define STEP(j) do {                                                         \
    const float uztwm = dA_##j.x, uzfwm = dA_##j.y;                          \
    const float inv_uztwm = dB_##j.x, inv_uzfwm = dB_##j.y;                  \
    const float inv_uzsum = dC_##j.x, lztwm = dC_##j.y;                      \
    const float inv_lztwm = dD_##j.x, pbase = dD_##j.y;                      \
    const float lzfwpm = dE_##j.x, lzfwsm = dE_##j.y;                        \
    const float pz = dF_##j.x, inv_defmax = dF_##j.y;                        \
    const float Ep = Ee_##j, kuz = kz_##j;                                   \
    const float qdir = c0_##j * Pp_##j;                                      \
    const float peff = Pp_##j - qdir;                                        \
    const float rud  = S2 * uztwm - S1 * uzfwm;                              \
    const float ru   = (rud > 0.0f) ? rud * inv_uzsum : 0.0f;                \
    const float euztw = fminf(S1 * inv_uztwm * Ep, S1);                      \
    const float twexu = (S1 >= uztwm) ? peff : 0.0f;                         \
    const float qsur  = (S2 >= uzfwm) ? twexu : 0.0f;                        \
    const float qint  = kuz * S2;                                            \
    const float euzfw = fminf(fmaxf(0.0f, Ep - euztw), S2);                  \
    const float deficit = fmaxf(1e-8f, lztwm - S3)                           \
                        + fmaxf(1e-8f, lzfwpm - S4)                          \
                        + fmaxf(1e-8f, lzfwsm - S5);                         \
    const float powterm = fexp2(e1 * flog2(deficit * inv_defmax));           \
    float pc = (pbase + pz * powterm) * (S2 * inv_uzfwm);                    \
    pc = fmaxf(0.0f, fminf(pc, S2));                                         \
    const float pctw  = (1.0f - pfree) * pc;                                 \
    const float elztw = fminf(S3 * inv_lztwm                                 \
                              * fmaxf(0.0f, Ep - euztw - euzfw), S3);        \
    const float twexl = (S3 >= lztwm) ? pctw : 0.0f;                         \
    const float aa  = fmaxf(0.0f, lzfwpm - S4) * lzfwsm;                     \
    const float bb  = fmaxf(0.0f, lzfwsm - S5) * lzfwpm;                     \
    const float den = aa + bb;                                               \
    const float pm  = lzfwpm + lzfwsm;                                       \
    const float fp  = ((den > 0.0f) ? aa : lzfwpm)                           \
                    * frcp((den > 0.0f) ? den : pm);                         \
    const float fs  = 1.0f - fp;                                             \
    const float twexlp = fp * twexl;                                         \
    const float twexls = fs * twexl;                                         \
    const float pcfwp  = pfree * fp * pc;                                    \
    const float pcfws  = pfree * fs * pc;                                    \
    const bool rlm = S3 * pm < (S4 + S5) * lztwm;                            \
    const float rlp = rlm ? (S4 * lztwm - S3 * lzfwpm) * inv_defmax : 0.0f;  \
    const float rls = rlm ? (S5 * lztwm - S3 * lzfwsm) * inv_defmax : 0.0f;  \
    const float qbfp = klzp * S4;                                            \
    const float qbfs = klzs * S5;                                            \
    S1 = fmaxf(S1 + peff + ru - euztw - twexu, SMINV);                       \
    S2 = fmaxf(S2 + twexu - euzfw - qsur - qint - ru - pc, SMINV);           \
    S3 = fmaxf(S3 + pctw + rlp + rls - elztw - twexl, SMINV);                \
    S4 = fmaxf(S4 + twexlp + pcfwp - rlp - qbfp, SMINV);                     \
    S5 = fmaxf(S5 + twexls + pcfws - rls - qbfs, SMINV);                     \
    smq[(j) * 64 + lane] = qdir + qsur + qint + qbfp + qbfs;                 \
    sme[(j) * 64 + lane] = euztw + euzfw + elztw;                            \
} while (0)

__global__ __launch_bounds__(192, 1) void sacsma_kernel(
    const float* __restrict__ x,     // [NSTEP][NGRID][3]
    const float* __restrict__ par,   // [NSTEP][NGRID][11][8]
    float* __restrict__ out)         // [NSTEP][NGRID][2]
{
    __shared__ __align__(16) float lds[16000];   // 64000 B

    const int wave = threadIdx.x >> 6;
    const int lane = threadIdx.x & 63;
    const int g0   = blockIdx.x * 8;
    const int gl   = lane >> 3;
    const int mu   = lane & 7;
    const int g    = g0 + gl;

    if (wave == 0) {
        // ===== DMA producer: issue batch i+1 FIRST, then counted wait for batch i =====
        const float* pp = par + (size_t)g * 88 + mu;
        int xl = lane; if (xl >= 24) xl -= 24; if (xl >= 24) xl -= 24;
        const int xq = xl / 3;
        const float* px = x + (g0 + xq) * 3 + (xl - xq * 3);

        // prologue: batch 0 -> raw region 0
        #pragma unroll
        for (int j = 0; j < 5; ++j)
            issue_slot(pp, px, j, lds + j * RAW_SLOT);

        for (int i = 0; i < 75; ++i) {
            if (i <= 71) {
                const int b = i + 1;                       // batches 1..72
                float* dst = lds + (b & 3) * RAW_REG;
                const int tb = 5 * b;
                #pragma unroll
                for (int j = 0; j < 5; ++j)
                    issue_slot(pp, px, tb + j, dst + j * RAW_SLOT);
                // batch i (issued one full iteration ago) must be retired;
                // the 30 newest outstanding are batch i+1's.
                asm volatile("s_waitcnt vmcnt(30)" ::: "memory");
            } else {
                asm volatile("s_waitcnt vmcnt(0)" ::: "memory");
            }
            asm volatile("s_barrier" ::: "memory");
        }
    } else if (wave == 1) {
        // ===== transform wave: raw -> derived (param-only math, off the S-chain) =====
        const float* ps = par + ((size_t)(NSTEP - 1) * NGRID + g) * 88 + mu;
        const float f3   = 0.005f + ps[6 * 8] * 0.99f;
        const float f4   = 0.005f + ps[7 * 8] * 0.99f;
        const float klzp = ps[9 * 8];
        const float klzs = ps[10 * 8];

        for (int i = 0; i < 75; ++i) {
            if (i >= 1 && i <= 73) {
                const int b = i - 1;                       // batches 0..72
                const float* rreg = lds + (b & 3) * RAW_REG;
                float* dregf = lds + DER_BASE + (b & 1) * DER_REG;
                #pragma unroll
                for (int j = 0; j < 5; ++j) {
                    const float* rb = rreg + j * RAW_SLOT;
                    float2* db = reinterpret_cast<float2*>(dregf + j * DER_SLOT);

                    const float c1 = rb[64 + lane];
                    const float c2 = rb[128 + lane];
                    const float c3 = rb[192 + lane];

                    const float smaxv = 1.0f + c1 * 1999.0f;
                    const float f1 = 0.005f + c2 * 0.99f;
                    const float f2 = 0.005f + c3 * 0.99f;
                    const float uztwm = f1 * smaxv;
                    float rem = smaxv - uztwm;
                    const float uzfwm = fmaxf(CAPMIN, f2 * rem);
                    rem -= uzfwm;
                    const float lztwm = fmaxf(CAPMIN, f3 * rem);
                    rem -= lztwm;
                    const float lzfwpm = fmaxf(CAPMIN, f4 * rem);
                    const float lzfwsm = fmaxf(CAPMIN, (1.0f - f4) * rem);
                    const float pbase = lzfwpm * klzp + lzfwsm * klzs;
                    const float pz = fminf(lztwm + lzfwsm * (1.0f - klzs)
                                           + lzfwpm * (1.0f - klzp),
                                           100000.0f * pbase);
                    const float inv_uztwm = frcp(uztwm);
                    const float inv_uzfwm = frcp(uzfwm);
                    const float inv_lztwm = frcp(lztwm);
                    const float inv_uzsum = frcp(uztwm + uzfwm);
                    const float inv_defmax = frcp(lztwm + lzfwpm + lzfwsm);

                    db[0 * 64 + lane] = make_float2(uztwm, uzfwm);
                    db[1 * 64 + lane] = make_float2(inv_uztwm, inv_uzfwm);
                    db[2 * 64 + lane] = make_float2(inv_uzsum, lztwm);
                    db[3 * 64 + lane] = make_float2(inv_lztwm, pbase);
                    db[4 * 64 + lane] = make_float2(lzfwpm, lzfwsm);
                    db[5 * 64 + lane] = make_float2(pz, inv_defmax);
                }
                asm volatile("s_waitcnt lgkmcnt(0)" ::: "memory");
            }
            asm volatile("s_barrier" ::: "memory");
        }
    } else {
        // ===== state wave: pure recurrence; all LDS reads hoisted per 5-step block =====
        const float* ps = par + ((size_t)(NSTEP - 1) * NGRID + g) * 88 + mu;
        const float e1    = 1.0f + ps[5 * 8] * 7.0f;
        const float pfree = ps[8 * 8];
        const float klzp  = ps[9 * 8];
        const float klzs  = ps[10 * 8];

        float S1 = 0.001f, S2 = 0.001f, S3 = 0.001f, S4 = 0.001f, S5 = 0.001f;
        float* smq = lds + SMQ_BASE;
        float* sme = lds + SME_BASE;
        const int gl3 = gl * 3;

        for (int i = 0; i < 75; ++i) {
            if (i >= 2) {
                const int b = i - 2;                       // batches 0..72
                const float* rreg = lds + (b & 3) * RAW_REG;
                const float2* dreg = reinterpret_cast<const float2*>(
                    lds + DER_BASE + (b & 1) * DER_REG);

                RDS(0) RDS(1) RDS(2) RDS(3) RDS(4)
                STEP(0); STEP(1); STEP(2); STEP(3); STEP(4);

                // batched mu-reduction + coalesced store for this 5-step block
                if (lane < 40) {
                    const int s  = lane >> 3;
                    const int gg = lane & 7;
                    const float4* q4 = reinterpret_cast<const float4*>(&smq[s * 64 + gg * 8]);
                    const float4* e4 = reinterpret_cast<const float4*>(&sme[s * 64 + gg * 8]);
                    const float4 qa = q4[0], qb = q4[1];
                    const float4 ea = e4[0], eb = e4[1];
                    const float qsum = ((qa.x + qa.y) + (qa.z + qa.w))
                                     + ((qb.x + qb.y) + (qb.z + qb.w));
                    const float esum = ((ea.x + ea.y) + (ea.z + ea.w))
                                     + ((eb.x + eb.y) + (eb.z + eb.w));
                    float2 o = make_float2(qsum * 0.125f, esum * 0.125f);
                    *reinterpret_cast<float2*>(
                        out + ((size_t)(5 * b + s) * NGRID + g0 + gg) * 2) = o;
                }
            }
            asm volatile("s_barrier" ::: "memory");
        }
    }
}

extern "C" void kernel_launch(void* const* d_in, const int* in_sizes, int n_in,
                              void* d_out, int out_size, void* d_ws, size_t ws_size,
                              hipStream_t stream) {
    const float* x   = (const float*)d_in[0];   // (365, 4000, 3)
    const float* par = (const float*)d_in[1];   // (365, 4000, 11, 8)
    float* out = (float*)d_out;                 // (365, 4000, 2)

    sacsma_kernel<<<NGRID / 8, 192, 0, stream>>>(x, par, out);  // 500 WGs x 3 waves
}